// Round 10
// baseline (283.907 us; speedup 1.0000x reference)
//
#include <hip/hip_runtime.h>
#include <hip/hip_fp16.h>

#define NN 100000
#define NE 1600000
#define FIN 128
#define FH 48
#define FO 32

// ---- partition parameters ----
#define LB 7                        // log2 nodes per coarse bucket
#define BKT_NODES 128               // nodes per bucket
#define NBKT ((NN + BKT_NODES - 1) / BKT_NODES)   // 782
#define PBLK 250                    // partition blocks
#define EPB (NE / PBLK)             // 6400 edges per partition block (exact)
#define EPB4 (EPB / 4)              // 1600 int4 per block
#define P2CAP 4096                  // LDS staging capacity (edges) in p2_bucket

// ---- gather parameters ----
#define GNPB 42                     // nodes/block (6 lanes each -> 252 of 256 active)

// fp16 pack/unpack helpers (storage fp16, arithmetic fp32)
__device__ inline float2 h2f2(unsigned int u) {
  __half2 h = __builtin_bit_cast(__half2, u);
  return __half22float2(h);
}
__device__ inline unsigned int f2h2(float a, float b) {
  __half2 h = __floats2half2_rn(a, b);
  return __builtin_bit_cast(unsigned int, h);
}

// ================= CSR build: block-ranked two-level partition =================

__global__ __launch_bounds__(256) void p1_hist(const int4* __restrict__ dst4, int* __restrict__ H) {
  __shared__ int hist[NBKT];
  const int t = threadIdx.x, blk = blockIdx.x;
  for (int i = t; i < NBKT; i += 256) hist[i] = 0;
  __syncthreads();
  const int k0 = blk * EPB4;
  for (int k = t; k < EPB4; k += 256) {
    int4 d = dst4[k0 + k];
    atomicAdd(&hist[d.x >> LB], 1);
    atomicAdd(&hist[d.y >> LB], 1);
    atomicAdd(&hist[d.z >> LB], 1);
    atomicAdd(&hist[d.w >> LB], 1);
  }
  __syncthreads();
  for (int i = t; i < NBKT; i += 256) H[blk * NBKT + i] = hist[i];
}

// column prefix in XCD-major block order (same-XCD writers get adjacent sub-ranges)
__global__ __launch_bounds__(256) void p1_colscan(int* __restrict__ H, int* __restrict__ tot) {
  int b = blockIdx.x * 256 + threadIdx.x;
  if (b >= NBKT) return;
  int run = 0;
  for (int xcd = 0; xcd < 8; ++xcd) {
    for (int blk = xcd; blk < PBLK; blk += 8) {
      int v = H[blk * NBKT + b];
      H[blk * NBKT + b] = run;
      run += v;
    }
  }
  tot[b] = run;
}

__global__ __launch_bounds__(256) void p1_scan(const int* __restrict__ tot, int* __restrict__ base,
                                               int* __restrict__ off) {
  __shared__ int s[256];
  const int t = threadIdx.x;
  int c[4]; int sum = 0;
  #pragma unroll
  for (int k = 0; k < 4; ++k) {
    int idx = 4 * t + k;
    c[k] = (idx < NBKT) ? tot[idx] : 0;
    sum += c[k];
  }
  s[t] = sum;
  __syncthreads();
  for (int o = 1; o < 256; o <<= 1) {
    int v = (t >= o) ? s[t - o] : 0;
    __syncthreads();
    s[t] += v;
    __syncthreads();
  }
  int run = s[t] - sum;
  #pragma unroll
  for (int k = 0; k < 4; ++k) {
    int idx = 4 * t + k;
    if (idx < NBKT) base[idx] = run;
    run += c[k];
  }
  if (t == 255) { base[NBKT] = run; off[NN] = run; }  // run == NE
}

// ranked scatter. Entry packs local_dst(7b)<<17 | src(17b).
__global__ __launch_bounds__(256) void p1_scatter(const int4* __restrict__ src4, const int4* __restrict__ dst4,
                                                  const int* __restrict__ H, const int* __restrict__ base,
                                                  int* __restrict__ pairs) {
  __shared__ int cur[NBKT];
  const int t = threadIdx.x, blk = blockIdx.x;
  for (int i = t; i < NBKT; i += 256) cur[i] = base[i] + H[blk * NBKT + i];
  __syncthreads();
  const int k0 = blk * EPB4;
  for (int k = t; k < EPB4; k += 256) {
    int4 s = src4[k0 + k];
    int4 d = dst4[k0 + k];
    int b0 = d.x >> LB, b1 = d.y >> LB, b2 = d.z >> LB, b3 = d.w >> LB;
    int p0 = atomicAdd(&cur[b0], 1);
    pairs[p0] = s.x | ((d.x & (BKT_NODES - 1)) << 17);
    int p1 = atomicAdd(&cur[b1], 1);
    pairs[p1] = s.y | ((d.y & (BKT_NODES - 1)) << 17);
    int p2 = atomicAdd(&cur[b2], 1);
    pairs[p2] = s.z | ((d.z & (BKT_NODES - 1)) << 17);
    int p3 = atomicAdd(&cur[b3], 1);
    pairs[p3] = s.w | ((d.w & (BKT_NODES - 1)) << 17);
  }
}

// per-bucket counting sort; bucket staged in LDS (global fallback for oversize)
__global__ __launch_bounds__(256) void p2_bucket(const int* __restrict__ pairs, const int* __restrict__ base,
                                                 int* __restrict__ csr, int* __restrict__ off,
                                                 float* __restrict__ dinv) {
  __shared__ int stage[P2CAP];
  __shared__ int cnt[BKT_NODES];
  __shared__ int s[BKT_NODES];
  const int t = threadIdx.x, b = blockIdx.x;
  const int j0 = base[b], j1 = base[b + 1];
  const int ne = j1 - j0;
  const bool fits = (ne <= P2CAP);

  if (t < BKT_NODES) cnt[t] = 0;
  if (fits) {
    for (int j = t; j < ne; j += 256) stage[j] = pairs[j0 + j];
  }
  __syncthreads();
  if (fits) {
    for (int j = t; j < ne; j += 256) atomicAdd(&cnt[stage[j] >> 17], 1);
  } else {
    for (int j = j0 + t; j < j1; j += 256) atomicAdd(&cnt[pairs[j] >> 17], 1);
  }
  __syncthreads();
  int myc = 0;
  if (t < BKT_NODES) { myc = cnt[t]; s[t] = myc; }
  __syncthreads();
  for (int o = 1; o < BKT_NODES; o <<= 1) {
    int v = (t >= o && t < BKT_NODES) ? s[t - o] : 0;
    __syncthreads();
    if (t < BKT_NODES) s[t] += v;
    __syncthreads();
  }
  int loc = 0;
  if (t < BKT_NODES) loc = s[t] - myc;
  const int n = b * BKT_NODES + t;
  if (t < BKT_NODES && n < NN) {
    off[n] = j0 + loc;
    dinv[n] = rsqrtf((float)myc + 1.0f);  // +1 self-loop
  }
  __syncthreads();
  if (t < BKT_NODES) s[t] = loc;
  __syncthreads();
  if (fits) {
    for (int j = t; j < ne; j += 256) {
      int p = stage[j];
      int pos = atomicAdd(&s[p >> 17], 1);
      csr[j0 + pos] = p & 0x1FFFF;
    }
  } else {
    for (int j = j0 + t; j < j1; j += 256) {
      int p = pairs[j];
      int pos = atomicAdd(&s[p >> 17], 1);
      csr[j0 + pos] = p & 0x1FFFF;
    }
  }
}

// ================= layer-1 dense: t1h = fp16(dinv * (x @ W1)) =================

__global__ __launch_bounds__(256) void k_gemm1(const float* __restrict__ x, const float* __restrict__ W1,
                                               const float* __restrict__ dinv, __half* __restrict__ t1h) {
  __shared__ float xs[64][132];
  __shared__ float ws[FIN][FH];
  const int t = threadIdx.x;
  const int row0 = blockIdx.x * 64;

  for (int i = t; i < FIN * FH; i += 256) ws[i / FH][i % FH] = W1[i];
  for (int i = t; i < 64 * (FIN / 4); i += 256) {
    int r = i >> 5, c4 = i & 31;
    float4 v = make_float4(0.f, 0.f, 0.f, 0.f);
    if (row0 + r < NN) v = ((const float4*)x)[(size_t)(row0 + r) * (FIN / 4) + c4];
    xs[r][c4 * 4 + 0] = v.x; xs[r][c4 * 4 + 1] = v.y;
    xs[r][c4 * 4 + 2] = v.z; xs[r][c4 * 4 + 3] = v.w;
  }
  __syncthreads();

  const int row = t >> 2;
  const int cg  = (t & 3) * 12;
  float acc[12];
  #pragma unroll
  for (int j = 0; j < 12; ++j) acc[j] = 0.f;

  #pragma unroll 4
  for (int k = 0; k < FIN; ++k) {
    float xv = xs[row][k];
    const float4* wp = (const float4*)&ws[k][cg];
    float4 w0 = wp[0], w1 = wp[1], w2 = wp[2];
    acc[0] += xv * w0.x; acc[1] += xv * w0.y; acc[2]  += xv * w0.z; acc[3]  += xv * w0.w;
    acc[4] += xv * w1.x; acc[5] += xv * w1.y; acc[6]  += xv * w1.z; acc[7]  += xv * w1.w;
    acc[8] += xv * w2.x; acc[9] += xv * w2.y; acc[10] += xv * w2.z; acc[11] += xv * w2.w;
  }

  const int grow = row0 + row;
  if (grow < NN) {
    const float dv = dinv[grow];
    #pragma unroll
    for (int j = 0; j < 12; ++j) acc[j] *= dv;
    uint2* p = (uint2*)(t1h + (size_t)grow * FH + cg);
    p[0] = make_uint2(f2h2(acc[0], acc[1]), f2h2(acc[2],  acc[3]));
    p[1] = make_uint2(f2h2(acc[4], acc[5]), f2h2(acc[6],  acc[7]));
    p[2] = make_uint2(f2h2(acc[8], acc[9]), f2h2(acc[10], acc[11]));
  }
}

// ---- gather core: 6 lanes/node, uint4 loads, direct csr reads (lane-merged),
//      pure row-sum (premultiplied feats), unroll 8 ----

#define ACC8(R)                                                                  \
  { float2 q0 = h2f2(R.x), q1 = h2f2(R.y), q2 = h2f2(R.z), q3 = h2f2(R.w);       \
    a[0] += q0.x; a[1] += q0.y; a[2] += q1.x; a[3] += q1.y;                      \
    a[4] += q2.x; a[5] += q2.y; a[6] += q3.x; a[7] += q3.y; }

#define GATHER_SUM(FEAT, SS)                                                     \
  {                                                                              \
    int j = jb;                                                                  \
    for (; j + 8 <= je; j += 8) {                                                \
      int s0 = SS[j],     s1 = SS[j + 1], s2 = SS[j + 2], s3 = SS[j + 3];        \
      int s4 = SS[j + 4], s5 = SS[j + 5], s6 = SS[j + 6], s7 = SS[j + 7];        \
      uint4 r0 = FEAT[(size_t)s0 * 6 + f8];                                      \
      uint4 r1 = FEAT[(size_t)s1 * 6 + f8];                                      \
      uint4 r2 = FEAT[(size_t)s2 * 6 + f8];                                      \
      uint4 r3 = FEAT[(size_t)s3 * 6 + f8];                                      \
      uint4 r4 = FEAT[(size_t)s4 * 6 + f8];                                      \
      uint4 r5 = FEAT[(size_t)s5 * 6 + f8];                                      \
      uint4 r6 = FEAT[(size_t)s6 * 6 + f8];                                      \
      uint4 r7 = FEAT[(size_t)s7 * 6 + f8];                                      \
      ACC8(r0) ACC8(r1) ACC8(r2) ACC8(r3) ACC8(r4) ACC8(r5) ACC8(r6) ACC8(r7)    \
    }                                                                            \
    for (; j + 4 <= je; j += 4) {                                                \
      int s0 = SS[j], s1 = SS[j + 1], s2 = SS[j + 2], s3 = SS[j + 3];            \
      uint4 r0 = FEAT[(size_t)s0 * 6 + f8];                                      \
      uint4 r1 = FEAT[(size_t)s1 * 6 + f8];                                      \
      uint4 r2 = FEAT[(size_t)s2 * 6 + f8];                                      \
      uint4 r3 = FEAT[(size_t)s3 * 6 + f8];                                      \
      ACC8(r0) ACC8(r1) ACC8(r2) ACC8(r3)                                        \
    }                                                                            \
    for (; j < je; ++j) {                                                        \
      int s = SS[j];                                                             \
      uint4 r = FEAT[(size_t)s * 6 + f8];                                        \
      ACC8(r)                                                                    \
    }                                                                            \
  }

// ================= layer-1 gather: h16 = fp16(dinv * relu(dinv*S + b1)) =================
// zero LDS -> max occupancy; csr read direct (6 lanes issue identical addrs -> merged)

__global__ __launch_bounds__(256, 6) void k_gather1(const int* __restrict__ off, const int* __restrict__ csr,
                                                    const __half* __restrict__ feat16, const float* __restrict__ dinv,
                                                    const float* __restrict__ bias, __half* __restrict__ out16) {
  const int t = threadIdx.x;
  const int local = t / 6;
  const int f8 = t - local * 6;
  const int node = blockIdx.x * GNPB + local;
  if (local >= GNPB || node >= NN) return;

  const uint4* feat = (const uint4*)feat16;
  uint4 rs = feat[(size_t)node * 6 + f8];
  float a[8];
  {
    float2 q0 = h2f2(rs.x), q1 = h2f2(rs.y), q2 = h2f2(rs.z), q3 = h2f2(rs.w);
    a[0] = q0.x; a[1] = q0.y; a[2] = q1.x; a[3] = q1.y;
    a[4] = q2.x; a[5] = q2.y; a[6] = q3.x; a[7] = q3.y;
  }

  const int jb = off[node];
  const int je = off[node + 1];
  GATHER_SUM(feat, csr)

  const float di = dinv[node];
  const float4* b4 = (const float4*)(bias + f8 * 8);
  float4 bb0 = b4[0], bb1 = b4[1];
  a[0] = di * fmaxf(di * a[0] + bb0.x, 0.f); a[1] = di * fmaxf(di * a[1] + bb0.y, 0.f);
  a[2] = di * fmaxf(di * a[2] + bb0.z, 0.f); a[3] = di * fmaxf(di * a[3] + bb0.w, 0.f);
  a[4] = di * fmaxf(di * a[4] + bb1.x, 0.f); a[5] = di * fmaxf(di * a[5] + bb1.y, 0.f);
  a[6] = di * fmaxf(di * a[6] + bb1.z, 0.f); a[7] = di * fmaxf(di * a[7] + bb1.w, 0.f);
  uint4 o;
  o.x = f2h2(a[0], a[1]); o.y = f2h2(a[2], a[3]);
  o.z = f2h2(a[4], a[5]); o.w = f2h2(a[6], a[7]);
  ((uint4*)out16)[(size_t)node * 6 + f8] = o;
}

// ================= layer-2 gather: aggf = fp32(dinv * S) (zero LDS) =================

__global__ __launch_bounds__(256, 6) void k_gather2(const int* __restrict__ off, const int* __restrict__ csr,
                                                    const __half* __restrict__ feat16, const float* __restrict__ dinv,
                                                    float* __restrict__ aggf) {
  const int t = threadIdx.x;
  const int local = t / 6;
  const int f8 = t - local * 6;
  const int node = blockIdx.x * GNPB + local;
  if (local >= GNPB || node >= NN) return;

  const uint4* feat = (const uint4*)feat16;
  uint4 rs = feat[(size_t)node * 6 + f8];
  float a[8];
  {
    float2 q0 = h2f2(rs.x), q1 = h2f2(rs.y), q2 = h2f2(rs.z), q3 = h2f2(rs.w);
    a[0] = q0.x; a[1] = q0.y; a[2] = q1.x; a[3] = q1.y;
    a[4] = q2.x; a[5] = q2.y; a[6] = q3.x; a[7] = q3.y;
  }

  const int jb = off[node];
  const int je = off[node + 1];
  GATHER_SUM(feat, csr)

  const float di = dinv[node];
  float4* ap = (float4*)(aggf + (size_t)node * FH + f8 * 8);
  ap[0] = make_float4(di * a[0], di * a[1], di * a[2], di * a[3]);
  ap[1] = make_float4(di * a[4], di * a[5], di * a[6], di * a[7]);
}

// ================= final dense (streaming): out = aggf@[Wmu|Wls] + [bmu|bls] =================

__global__ __launch_bounds__(256) void k_dense(const float* __restrict__ aggf,
                                               const float* __restrict__ Wmu, const float* __restrict__ bmu,
                                               const float* __restrict__ Wls, const float* __restrict__ bls,
                                               float* __restrict__ out) {
  __shared__ float wall[FH][2 * FO];      // [48][64]
  __shared__ float as[64][FH + 1];        // 64 x 49
  const int t = threadIdx.x;
  const int n0 = blockIdx.x * 64;

  for (int i = t; i < FH * 2 * FO; i += 256) {
    int k = i >> 6, c = i & 63;
    wall[k][c] = (c < FO) ? Wmu[k * FO + c] : Wls[k * FO + (c - FO)];
  }
  for (int i = t; i < 64 * FH; i += 256) {
    int r = i / FH, c = i - r * FH;
    as[r][c] = (n0 + r < NN) ? aggf[(size_t)(n0 + r) * FH + c] : 0.f;
  }
  __syncthreads();

  const int ln = t >> 2;            // 64 nodes
  const int cb = (t & 3) * 16;      // 16 outputs each
  float acc[16];
  #pragma unroll
  for (int j = 0; j < 16; ++j) acc[j] = (cb + j < FO) ? bmu[cb + j] : bls[cb + j - FO];

  #pragma unroll 4
  for (int k = 0; k < FH; ++k) {
    float av = as[ln][k];
    const float4* wp = (const float4*)&wall[k][cb];
    float4 w0 = wp[0], w1 = wp[1], w2 = wp[2], w3 = wp[3];
    acc[0]  += av * w0.x; acc[1]  += av * w0.y; acc[2]  += av * w0.z; acc[3]  += av * w0.w;
    acc[4]  += av * w1.x; acc[5]  += av * w1.y; acc[6]  += av * w1.z; acc[7]  += av * w1.w;
    acc[8]  += av * w2.x; acc[9]  += av * w2.y; acc[10] += av * w2.z; acc[11] += av * w2.w;
    acc[12] += av * w3.x; acc[13] += av * w3.y; acc[14] += av * w3.z; acc[15] += av * w3.w;
  }

  const int grow = n0 + ln;
  if (grow < NN) {
    float4* po;
    if (cb < FO) po = (float4*)(out + (size_t)grow * FO + cb);
    else         po = (float4*)(out + (size_t)NN * FO + (size_t)grow * FO + (cb - FO));
    po[0] = make_float4(acc[0],  acc[1],  acc[2],  acc[3]);
    po[1] = make_float4(acc[4],  acc[5],  acc[6],  acc[7]);
    po[2] = make_float4(acc[8],  acc[9],  acc[10], acc[11]);
    po[3] = make_float4(acc[12], acc[13], acc[14], acc[15]);
  }
}

// ================= launch =================

extern "C" void kernel_launch(void* const* d_in, const int* in_sizes, int n_in,
                              void* d_out, int out_size, void* d_ws, size_t ws_size,
                              hipStream_t stream) {
  const float* x   = (const float*)d_in[0];
  const int*   ei  = (const int*)d_in[1];   // [2, NE] flat: src then dst
  const float* W1  = (const float*)d_in[2];
  const float* b1  = (const float*)d_in[3];
  const float* Wmu = (const float*)d_in[4];
  const float* bmu = (const float*)d_in[5];
  const float* Wls = (const float*)d_in[6];
  const float* bls = (const float*)d_in[7];
  float* out = (float*)d_out;

  const int4* src4 = (const int4*)ei;
  const int4* dst4 = (const int4*)(ei + NE);

  // workspace layout (~52.5 MB, 16B-aligned boundaries)
  char* base_p = (char*)d_ws;
  int*    pairs = (int*)base_p;                          // NE*4 = 6.4 MB
  int*    csr   = pairs + (size_t)NE;                    // 6.4 MB
  __half* t1h   = (__half*)(csr + (size_t)NE);           // NN*FH*2 = 9.6 MB
  __half* h16   = t1h + (size_t)NN * FH;                 // 9.6 MB
  float*  aggf  = (float*)(h16 + (size_t)NN * FH);       // NN*FH*4 = 19.2 MB
  int*    H     = (int*)(aggf + (size_t)NN * FH);        // PBLK*NBKT = 782 KB
  int*    tot   = H + (size_t)PBLK * NBKT;               // NBKT
  int*    bkb   = tot + NBKT;                            // NBKT+1
  int*    off   = bkb + NBKT + 1;                        // NN+1
  float*  dinv  = (float*)(off + NN + 1);                // NN

  // CSR build
  p1_hist   <<<PBLK, 256, 0, stream>>>(dst4, H);
  p1_colscan<<<(NBKT + 255) / 256, 256, 0, stream>>>(H, tot);
  p1_scan   <<<1, 256, 0, stream>>>(tot, bkb, off);
  p1_scatter<<<PBLK, 256, 0, stream>>>(src4, dst4, H, bkb, pairs);
  p2_bucket <<<NBKT, 256, 0, stream>>>(pairs, bkb, csr, off, dinv);

  // layer 1: t1h = fp16(dinv * x@W1) ; h16 = fp16(dinv * relu(dinv*S + b1))
  k_gemm1<<<(NN + 63) / 64, 256, 0, stream>>>(x, W1, dinv, t1h);
  k_gather1<<<(NN + GNPB - 1) / GNPB, 256, 0, stream>>>(off, csr, t1h, dinv, b1, h16);

  // layer 2: aggf = fp32(dinv*S) ; out = aggf@[Wmu|Wls] + [bmu|bls]
  k_gather2<<<(NN + GNPB - 1) / GNPB, 256, 0, stream>>>(off, csr, h16, dinv, aggf);
  k_dense<<<(NN + 63) / 64, 256, 0, stream>>>(aggf, Wmu, bmu, Wls, bls, out);
}

// Round 11
// 272.234 us; speedup vs baseline: 1.0429x; 1.0429x over previous
//
#include <hip/hip_runtime.h>
#include <hip/hip_fp16.h>

#define NN 100000
#define NE 1600000
#define FIN 128
#define FH 48
#define FO 32

// ---- partition parameters ----
#define LB 7                        // log2 nodes per coarse bucket
#define BKT_NODES 128               // nodes per bucket
#define NBKT ((NN + BKT_NODES - 1) / BKT_NODES)   // 782
#define PBLK 250                    // partition blocks
#define EPB (NE / PBLK)             // 6400 edges per partition block (exact)
#define EPB4 (EPB / 4)              // 1600 int4 per block
#define P2CAP 4096                  // LDS staging capacity (edges) in p2_bucket

// ---- gather parameters ----
#define GNPB 42                     // nodes/block (6 lanes each -> 252 of 256 active)

// fp16 pack/unpack helpers (storage fp16, arithmetic fp32)
__device__ inline float2 h2f2(unsigned int u) {
  __half2 h = __builtin_bit_cast(__half2, u);
  return __half22float2(h);
}
__device__ inline unsigned int f2h2(float a, float b) {
  __half2 h = __floats2half2_rn(a, b);
  return __builtin_bit_cast(unsigned int, h);
}

// ================= CSR build: block-ranked two-level partition =================

__global__ __launch_bounds__(256) void p1_hist(const int4* __restrict__ dst4, int* __restrict__ H) {
  __shared__ int hist[NBKT];
  const int t = threadIdx.x, blk = blockIdx.x;
  for (int i = t; i < NBKT; i += 256) hist[i] = 0;
  __syncthreads();
  const int k0 = blk * EPB4;
  for (int k = t; k < EPB4; k += 256) {
    int4 d = dst4[k0 + k];
    atomicAdd(&hist[d.x >> LB], 1);
    atomicAdd(&hist[d.y >> LB], 1);
    atomicAdd(&hist[d.z >> LB], 1);
    atomicAdd(&hist[d.w >> LB], 1);
  }
  __syncthreads();
  for (int i = t; i < NBKT; i += 256) H[blk * NBKT + i] = hist[i];
}

// column prefix in XCD-major block order (same-XCD writers get adjacent sub-ranges)
__global__ __launch_bounds__(256) void p1_colscan(int* __restrict__ H, int* __restrict__ tot) {
  int b = blockIdx.x * 256 + threadIdx.x;
  if (b >= NBKT) return;
  int run = 0;
  for (int xcd = 0; xcd < 8; ++xcd) {
    for (int blk = xcd; blk < PBLK; blk += 8) {
      int v = H[blk * NBKT + b];
      H[blk * NBKT + b] = run;
      run += v;
    }
  }
  tot[b] = run;
}

__global__ __launch_bounds__(256) void p1_scan(const int* __restrict__ tot, int* __restrict__ base,
                                               int* __restrict__ off) {
  __shared__ int s[256];
  const int t = threadIdx.x;
  int c[4]; int sum = 0;
  #pragma unroll
  for (int k = 0; k < 4; ++k) {
    int idx = 4 * t + k;
    c[k] = (idx < NBKT) ? tot[idx] : 0;
    sum += c[k];
  }
  s[t] = sum;
  __syncthreads();
  for (int o = 1; o < 256; o <<= 1) {
    int v = (t >= o) ? s[t - o] : 0;
    __syncthreads();
    s[t] += v;
    __syncthreads();
  }
  int run = s[t] - sum;
  #pragma unroll
  for (int k = 0; k < 4; ++k) {
    int idx = 4 * t + k;
    if (idx < NBKT) base[idx] = run;
    run += c[k];
  }
  if (t == 255) { base[NBKT] = run; off[NN] = run; }  // run == NE
}

// ranked scatter. Entry packs local_dst(7b)<<17 | src(17b).
__global__ __launch_bounds__(256) void p1_scatter(const int4* __restrict__ src4, const int4* __restrict__ dst4,
                                                  const int* __restrict__ H, const int* __restrict__ base,
                                                  int* __restrict__ pairs) {
  __shared__ int cur[NBKT];
  const int t = threadIdx.x, blk = blockIdx.x;
  for (int i = t; i < NBKT; i += 256) cur[i] = base[i] + H[blk * NBKT + i];
  __syncthreads();
  const int k0 = blk * EPB4;
  for (int k = t; k < EPB4; k += 256) {
    int4 s = src4[k0 + k];
    int4 d = dst4[k0 + k];
    int b0 = d.x >> LB, b1 = d.y >> LB, b2 = d.z >> LB, b3 = d.w >> LB;
    int p0 = atomicAdd(&cur[b0], 1);
    pairs[p0] = s.x | ((d.x & (BKT_NODES - 1)) << 17);
    int p1 = atomicAdd(&cur[b1], 1);
    pairs[p1] = s.y | ((d.y & (BKT_NODES - 1)) << 17);
    int p2 = atomicAdd(&cur[b2], 1);
    pairs[p2] = s.z | ((d.z & (BKT_NODES - 1)) << 17);
    int p3 = atomicAdd(&cur[b3], 1);
    pairs[p3] = s.w | ((d.w & (BKT_NODES - 1)) << 17);
  }
}

// per-bucket counting sort; bucket staged in LDS (global fallback for oversize)
__global__ __launch_bounds__(256) void p2_bucket(const int* __restrict__ pairs, const int* __restrict__ base,
                                                 int* __restrict__ csr, int* __restrict__ off,
                                                 float* __restrict__ dinv) {
  __shared__ int stage[P2CAP];
  __shared__ int cnt[BKT_NODES];
  __shared__ int s[BKT_NODES];
  const int t = threadIdx.x, b = blockIdx.x;
  const int j0 = base[b], j1 = base[b + 1];
  const int ne = j1 - j0;
  const bool fits = (ne <= P2CAP);

  if (t < BKT_NODES) cnt[t] = 0;
  if (fits) {
    for (int j = t; j < ne; j += 256) stage[j] = pairs[j0 + j];
  }
  __syncthreads();
  if (fits) {
    for (int j = t; j < ne; j += 256) atomicAdd(&cnt[stage[j] >> 17], 1);
  } else {
    for (int j = j0 + t; j < j1; j += 256) atomicAdd(&cnt[pairs[j] >> 17], 1);
  }
  __syncthreads();
  int myc = 0;
  if (t < BKT_NODES) { myc = cnt[t]; s[t] = myc; }
  __syncthreads();
  for (int o = 1; o < BKT_NODES; o <<= 1) {
    int v = (t >= o && t < BKT_NODES) ? s[t - o] : 0;
    __syncthreads();
    if (t < BKT_NODES) s[t] += v;
    __syncthreads();
  }
  int loc = 0;
  if (t < BKT_NODES) loc = s[t] - myc;
  const int n = b * BKT_NODES + t;
  if (t < BKT_NODES && n < NN) {
    off[n] = j0 + loc;
    dinv[n] = rsqrtf((float)myc + 1.0f);  // +1 self-loop
  }
  __syncthreads();
  if (t < BKT_NODES) s[t] = loc;
  __syncthreads();
  if (fits) {
    for (int j = t; j < ne; j += 256) {
      int p = stage[j];
      int pos = atomicAdd(&s[p >> 17], 1);
      csr[j0 + pos] = p & 0x1FFFF;
    }
  } else {
    for (int j = j0 + t; j < j1; j += 256) {
      int p = pairs[j];
      int pos = atomicAdd(&s[p >> 17], 1);
      csr[j0 + pos] = p & 0x1FFFF;
    }
  }
}

// ================= layer-1 dense: t1h = fp16(dinv * (x @ W1)) =================
// Row-per-thread: 256 rows/block, acc[48] in registers, x streamed from global
// (64B-line reuse over 4 k-steps), W1 in LDS with wave-uniform broadcast reads.

__global__ __launch_bounds__(256) void k_gemm1(const float* __restrict__ x, const float* __restrict__ W1,
                                               const float* __restrict__ dinv, __half* __restrict__ t1h) {
  __shared__ float ws[FIN * FH];  // k-major [128][48], 24.6 KB
  const int t = threadIdx.x;
  for (int i = t; i < FIN * FH / 4; i += 256) ((float4*)ws)[i] = ((const float4*)W1)[i];
  __syncthreads();

  const int row = blockIdx.x * 256 + t;
  if (row >= NN) return;

  float acc[48];
  #pragma unroll
  for (int j = 0; j < 48; ++j) acc[j] = 0.f;

  const float4* xr = (const float4*)(x + (size_t)row * FIN);
  #pragma unroll 1
  for (int kk = 0; kk < FIN / 4; ++kk) {
    float4 xv = xr[kk];
    const float* wk = ws + (kk * 4) * FH;
    #pragma unroll
    for (int e = 0; e < 4; ++e) {
      const float xs_ = (e == 0) ? xv.x : (e == 1) ? xv.y : (e == 2) ? xv.z : xv.w;
      const float4* w4 = (const float4*)(wk + e * FH);
      #pragma unroll
      for (int c4 = 0; c4 < 12; ++c4) {
        float4 w = w4[c4];
        acc[c4 * 4 + 0] += xs_ * w.x;
        acc[c4 * 4 + 1] += xs_ * w.y;
        acc[c4 * 4 + 2] += xs_ * w.z;
        acc[c4 * 4 + 3] += xs_ * w.w;
      }
    }
  }

  const float dv = dinv[row];
  uint4* po = (uint4*)(t1h + (size_t)row * FH);  // 96 B/row, 16B-aligned
  #pragma unroll
  for (int g = 0; g < 6; ++g) {
    uint4 o;
    o.x = f2h2(acc[g * 8 + 0] * dv, acc[g * 8 + 1] * dv);
    o.y = f2h2(acc[g * 8 + 2] * dv, acc[g * 8 + 3] * dv);
    o.z = f2h2(acc[g * 8 + 4] * dv, acc[g * 8 + 5] * dv);
    o.w = f2h2(acc[g * 8 + 6] * dv, acc[g * 8 + 7] * dv);
    po[g] = o;
  }
}

// ---- gather core: 6 lanes/node, uint4 loads, direct csr reads (lane-merged),
//      pure row-sum (premultiplied feats), unroll 8 ----

#define ACC8(R)                                                                  \
  { float2 q0 = h2f2(R.x), q1 = h2f2(R.y), q2 = h2f2(R.z), q3 = h2f2(R.w);       \
    a[0] += q0.x; a[1] += q0.y; a[2] += q1.x; a[3] += q1.y;                      \
    a[4] += q2.x; a[5] += q2.y; a[6] += q3.x; a[7] += q3.y; }

#define GATHER_SUM(FEAT, SS)                                                     \
  {                                                                              \
    int j = jb;                                                                  \
    for (; j + 8 <= je; j += 8) {                                                \
      int s0 = SS[j],     s1 = SS[j + 1], s2 = SS[j + 2], s3 = SS[j + 3];        \
      int s4 = SS[j + 4], s5 = SS[j + 5], s6 = SS[j + 6], s7 = SS[j + 7];        \
      uint4 r0 = FEAT[(size_t)s0 * 6 + f8];                                      \
      uint4 r1 = FEAT[(size_t)s1 * 6 + f8];                                      \
      uint4 r2 = FEAT[(size_t)s2 * 6 + f8];                                      \
      uint4 r3 = FEAT[(size_t)s3 * 6 + f8];                                      \
      uint4 r4 = FEAT[(size_t)s4 * 6 + f8];                                      \
      uint4 r5 = FEAT[(size_t)s5 * 6 + f8];                                      \
      uint4 r6 = FEAT[(size_t)s6 * 6 + f8];                                      \
      uint4 r7 = FEAT[(size_t)s7 * 6 + f8];                                      \
      ACC8(r0) ACC8(r1) ACC8(r2) ACC8(r3) ACC8(r4) ACC8(r5) ACC8(r6) ACC8(r7)    \
    }                                                                            \
    for (; j + 4 <= je; j += 4) {                                                \
      int s0 = SS[j], s1 = SS[j + 1], s2 = SS[j + 2], s3 = SS[j + 3];            \
      uint4 r0 = FEAT[(size_t)s0 * 6 + f8];                                      \
      uint4 r1 = FEAT[(size_t)s1 * 6 + f8];                                      \
      uint4 r2 = FEAT[(size_t)s2 * 6 + f8];                                      \
      uint4 r3 = FEAT[(size_t)s3 * 6 + f8];                                      \
      ACC8(r0) ACC8(r1) ACC8(r2) ACC8(r3)                                        \
    }                                                                            \
    for (; j < je; ++j) {                                                        \
      int s = SS[j];                                                             \
      uint4 r = FEAT[(size_t)s * 6 + f8];                                        \
      ACC8(r)                                                                    \
    }                                                                            \
  }

// ================= layer-1 gather: h16 = fp16(dinv * relu(dinv*S + b1)) =================
// zero LDS -> max occupancy; csr read direct (6 lanes issue identical addrs -> merged)

__global__ __launch_bounds__(256, 6) void k_gather1(const int* __restrict__ off, const int* __restrict__ csr,
                                                    const __half* __restrict__ feat16, const float* __restrict__ dinv,
                                                    const float* __restrict__ bias, __half* __restrict__ out16) {
  const int t = threadIdx.x;
  const int local = t / 6;
  const int f8 = t - local * 6;
  const int node = blockIdx.x * GNPB + local;
  if (local >= GNPB || node >= NN) return;

  const uint4* feat = (const uint4*)feat16;
  uint4 rs = feat[(size_t)node * 6 + f8];
  float a[8];
  {
    float2 q0 = h2f2(rs.x), q1 = h2f2(rs.y), q2 = h2f2(rs.z), q3 = h2f2(rs.w);
    a[0] = q0.x; a[1] = q0.y; a[2] = q1.x; a[3] = q1.y;
    a[4] = q2.x; a[5] = q2.y; a[6] = q3.x; a[7] = q3.y;
  }

  const int jb = off[node];
  const int je = off[node + 1];
  GATHER_SUM(feat, csr)

  const float di = dinv[node];
  const float4* b4 = (const float4*)(bias + f8 * 8);
  float4 bb0 = b4[0], bb1 = b4[1];
  a[0] = di * fmaxf(di * a[0] + bb0.x, 0.f); a[1] = di * fmaxf(di * a[1] + bb0.y, 0.f);
  a[2] = di * fmaxf(di * a[2] + bb0.z, 0.f); a[3] = di * fmaxf(di * a[3] + bb0.w, 0.f);
  a[4] = di * fmaxf(di * a[4] + bb1.x, 0.f); a[5] = di * fmaxf(di * a[5] + bb1.y, 0.f);
  a[6] = di * fmaxf(di * a[6] + bb1.z, 0.f); a[7] = di * fmaxf(di * a[7] + bb1.w, 0.f);
  uint4 o;
  o.x = f2h2(a[0], a[1]); o.y = f2h2(a[2], a[3]);
  o.z = f2h2(a[4], a[5]); o.w = f2h2(a[6], a[7]);
  ((uint4*)out16)[(size_t)node * 6 + f8] = o;
}

// ================= layer-2 fused: out = (dinv*S)@[Wmu|Wls] + [bmu|bls] =================
// gather phase zero-staging (direct csr); LDS only wall (12KB) + as2 (8.7KB) = 20.7KB

__global__ __launch_bounds__(256) void k_gather_gemm2(const int* __restrict__ off, const int* __restrict__ csr,
                                                      const __half* __restrict__ feat16, const float* __restrict__ dinv,
                                                      const float* __restrict__ Wmu, const float* __restrict__ bmu,
                                                      const float* __restrict__ Wls, const float* __restrict__ bls,
                                                      float* __restrict__ out) {
  __shared__ float wall[FH][2 * FO];      // [48][64] = 12 KB
  __shared__ float as2[GNPB][FH + 4];     // 42 x 52 = 8.7 KB (16B-aligned rows)
  const int t = threadIdx.x;
  const int n0 = blockIdx.x * GNPB;

  for (int i = t; i < FH * 2 * FO; i += 256) {
    int k = i >> 6, c = i & 63;
    wall[k][c] = (c < FO) ? Wmu[k * FO + c] : Wls[k * FO + (c - FO)];
  }

  const int local = t / 6;
  const int f8 = t - local * 6;
  const int node = n0 + local;
  const bool active = (local < GNPB) && (node < NN);

  if (active) {
    const uint4* feat = (const uint4*)feat16;
    uint4 rs = feat[(size_t)node * 6 + f8];
    float a[8];
    {
      float2 q0 = h2f2(rs.x), q1 = h2f2(rs.y), q2 = h2f2(rs.z), q3 = h2f2(rs.w);
      a[0] = q0.x; a[1] = q0.y; a[2] = q1.x; a[3] = q1.y;
      a[4] = q2.x; a[5] = q2.y; a[6] = q3.x; a[7] = q3.y;
    }
    const int jb = off[node];
    const int je = off[node + 1];
    GATHER_SUM(feat, csr)

    const float di = dinv[node];
    float* ap = &as2[local][f8 * 8];
    ap[0] = di * a[0]; ap[1] = di * a[1]; ap[2] = di * a[2]; ap[3] = di * a[3];
    ap[4] = di * a[4]; ap[5] = di * a[5]; ap[6] = di * a[6]; ap[7] = di * a[7];
  }
  __syncthreads();

  // dense phase: 42 nodes x 64 outputs strided over 256 threads
  for (int o = t; o < GNPB * 2 * FO; o += 256) {
    const int ln = o >> 6;
    const int c = o & 63;
    const int grow = n0 + ln;
    if (grow < NN) {
      float acc = (c < FO) ? bmu[c] : bls[c - FO];
      #pragma unroll
      for (int k = 0; k < FH; ++k) acc += as2[ln][k] * wall[k][c];
      if (c < FO) out[(size_t)grow * FO + c] = acc;
      else        out[(size_t)NN * FO + (size_t)grow * FO + (c - FO)] = acc;
    }
  }
}

// ================= launch =================

extern "C" void kernel_launch(void* const* d_in, const int* in_sizes, int n_in,
                              void* d_out, int out_size, void* d_ws, size_t ws_size,
                              hipStream_t stream) {
  const float* x   = (const float*)d_in[0];
  const int*   ei  = (const int*)d_in[1];   // [2, NE] flat: src then dst
  const float* W1  = (const float*)d_in[2];
  const float* b1  = (const float*)d_in[3];
  const float* Wmu = (const float*)d_in[4];
  const float* bmu = (const float*)d_in[5];
  const float* Wls = (const float*)d_in[6];
  const float* bls = (const float*)d_in[7];
  float* out = (float*)d_out;

  const int4* src4 = (const int4*)ei;
  const int4* dst4 = (const int4*)(ei + NE);

  // workspace layout (~33 MB, 16B-aligned boundaries)
  char* base_p = (char*)d_ws;
  int*    pairs = (int*)base_p;                          // NE*4 = 6.4 MB
  int*    csr   = pairs + (size_t)NE;                    // 6.4 MB
  __half* t1h   = (__half*)(csr + (size_t)NE);           // NN*FH*2 = 9.6 MB
  __half* h16   = t1h + (size_t)NN * FH;                 // 9.6 MB
  int*    H     = (int*)(h16 + (size_t)NN * FH);         // PBLK*NBKT = 782 KB
  int*    tot   = H + (size_t)PBLK * NBKT;               // NBKT
  int*    bkb   = tot + NBKT;                            // NBKT+1
  int*    off   = bkb + NBKT + 1;                        // NN+1
  float*  dinv  = (float*)(off + NN + 1);                // NN

  // CSR build
  p1_hist   <<<PBLK, 256, 0, stream>>>(dst4, H);
  p1_colscan<<<(NBKT + 255) / 256, 256, 0, stream>>>(H, tot);
  p1_scan   <<<1, 256, 0, stream>>>(tot, bkb, off);
  p1_scatter<<<PBLK, 256, 0, stream>>>(src4, dst4, H, bkb, pairs);
  p2_bucket <<<NBKT, 256, 0, stream>>>(pairs, bkb, csr, off, dinv);

  // layer 1: t1h = fp16(dinv * x@W1) ; h16 = fp16(dinv * relu(dinv*S + b1))
  k_gemm1<<<(NN + 255) / 256, 256, 0, stream>>>(x, W1, dinv, t1h);
  k_gather1<<<(NN + GNPB - 1) / GNPB, 256, 0, stream>>>(off, csr, t1h, dinv, b1, h16);

  // layer 2 fused: out = (dinv*S)@[Wmu|Wls] + [bmu|bls]
  k_gather_gemm2<<<(NN + GNPB - 1) / GNPB, 256, 0, stream>>>(
      off, csr, h16, dinv, Wmu, bmu, Wls, bls, out);
}